// Round 1
// baseline (514.743 us; speedup 1.0000x reference)
//
#include <hip/hip_runtime.h>
#include <float.h>
#include <math.h>

#define NB 128
#define NQ 16
#define ND 800
#define NE 300

// workspace layout (float offsets)
#define WS_SIM    0
#define WS_DNEPS  (NB*NQ*ND)              // dnorm + 1e-9        [NB][ND]
#define WS_CTXINV (WS_DNEPS + NB*ND)      // 1/(ctxnorm/9+1e-9)  [NB][ND]
#define WS_QNINV  (WS_CTXINV + NB*ND)     // 1/(qnorm+1e-9)      [NB][NQ]
#define WS_SCORES (WS_QNINV + NB*NQ)      // [NB][NQ][13]

__device__ __forceinline__ void ins6(float t[6], float v) {
    if (v > t[5]) t[5] = v;
    float a;
    if (t[5] > t[4]) { a = t[4]; t[4] = t[5]; t[5] = a; }
    if (t[4] > t[3]) { a = t[3]; t[3] = t[4]; t[4] = a; }
    if (t[3] > t[2]) { a = t[2]; t[2] = t[3]; t[3] = a; }
    if (t[2] > t[1]) { a = t[1]; t[1] = t[2]; t[2] = a; }
    if (t[1] > t[0]) { a = t[0]; t[0] = t[1]; t[1] = a; }
}

__device__ __forceinline__ void ins2(float& a1, float& a2, float v) {
    if (v > a2) a2 = v;
    if (a2 > a1) { float t = a1; a1 = a2; a2 = t; }
}

// merge two sorted-desc pairs -> top2 of union
__device__ __forceinline__ void merge2(float& a1, float& a2, float b1v, float b2v) {
    float hi = fmaxf(a1, b1v), lo = fminf(a1, b1v);
    a1 = hi;
    a2 = fmaxf(lo, fmaxf(a2, b2v));
}

// ---------------- kq: q-norm inverse + idf into scores[12] ----------------
__global__ __launch_bounds__(64) void kq(const int* __restrict__ qrls,
                                         const float* __restrict__ emb,
                                         const float* __restrict__ idf,
                                         float* __restrict__ ws) {
    int b = blockIdx.x;
    int l = threadIdx.x;
    int q = l & 15, part = l >> 4;
    int row = qrls[b * NQ + q];
    const float* p = emb + (size_t)row * NE;
    float s = 0.f;
    int e0 = part * 75;
    for (int k = 0; k < 75; ++k) { float v = p[e0 + k]; s += v * v; }
    s += __shfl_xor(s, 16);
    s += __shfl_xor(s, 32);
    if (part == 0) {
        ws[WS_QNINV + b * NQ + q] = 1.f / (sqrtf(s) + 1e-9f);
        ws[WS_SCORES + (b * NQ + q) * 13 + 12] = idf[row];
    }
}

// ---------------- kctx: per (b,d) doc-norm and context-norm ----------------
// 16 lanes per d (coalesced within each row), 16 d-groups per 256-thread block
__global__ __launch_bounds__(256) void kctx(const int* __restrict__ docw,
                                            const float* __restrict__ emb,
                                            float* __restrict__ ws) {
    int b = blockIdx.y;
    int lane16 = threadIdx.x & 15;
    int g = threadIdx.x >> 4;
    for (int pass = 0; pass < 4; ++pass) {
        int d = blockIdx.x * 64 + pass * 16 + g;
        if (d >= ND) continue;
        const float* rp[8];
        bool valid[8];
#pragma unroll
        for (int t = 0; t < 8; ++t) {
            int j = d - 4 + t;
            valid[t] = (j >= 0 && j < ND);
            int r = valid[t] ? docw[b * ND + j] : 0;
            rp[t] = emb + (size_t)r * NE;
        }
        float sq = 0.f, sqd = 0.f;
        for (int k = 0; k < 19; ++k) {
            int e = lane16 + k * 16;
            if (e < NE) {
                float wsum = 0.f;
#pragma unroll
                for (int t = 0; t < 8; ++t) {
                    if (valid[t]) {
                        float x = rp[t][e];
                        wsum += x;
                        if (t == 4) sqd += x * x;   // row j==d always valid
                    }
                }
                sq += wsum * wsum;
            }
        }
#pragma unroll
        for (int m = 1; m <= 8; m <<= 1) {
            sq  += __shfl_xor(sq, m);
            sqd += __shfl_xor(sqd, m);
        }
        if (lane16 == 0) {
            ws[WS_CTXINV + b * ND + d] = 1.f / (sqrtf(sq) * (1.f / 9.f) + 1e-9f);
            ws[WS_DNEPS  + b * ND + d] = sqrtf(sqd) + 1e-9f;
        }
    }
}

// ---------------- ksim: normalized sim matrix [NB][NQ][ND] ----------------
// grid (4, NB): 4 q per block; thread owns 4 d's (d3 clamped -> benign dup store)
__global__ __launch_bounds__(256) void ksim(const int* __restrict__ qrls,
                                            const int* __restrict__ docw,
                                            const float* __restrict__ emb,
                                            float* __restrict__ ws) {
    int b = blockIdx.y;
    int qg = blockIdx.x * 4;
    int tid = threadIdx.x;
    const float* qp[4];
    float qninv[4];
#pragma unroll
    for (int i = 0; i < 4; ++i) {
        int row = qrls[b * NQ + qg + i];         // wave-uniform -> scalar load
        qp[i] = emb + (size_t)row * NE;
        qninv[i] = ws[WS_QNINV + b * NQ + qg + i];
    }
    int d0 = tid, d1 = tid + 256, d2 = tid + 512, d3 = tid + 768;
    if (d3 >= ND) d3 = ND - 1;
    const float* p0 = emb + (size_t)docw[b * ND + d0] * NE;
    const float* p1 = emb + (size_t)docw[b * ND + d1] * NE;
    const float* p2 = emb + (size_t)docw[b * ND + d2] * NE;
    const float* p3 = emb + (size_t)docw[b * ND + d3] * NE;
    float acc0[4] = {0.f,0.f,0.f,0.f}, acc1[4] = {0.f,0.f,0.f,0.f};
    float acc2[4] = {0.f,0.f,0.f,0.f}, acc3[4] = {0.f,0.f,0.f,0.f};
    for (int e4 = 0; e4 < 75; ++e4) {
        float4 v0 = *(const float4*)(p0 + e4 * 4);
        float4 v1 = *(const float4*)(p1 + e4 * 4);
        float4 v2 = *(const float4*)(p2 + e4 * 4);
        float4 v3 = *(const float4*)(p3 + e4 * 4);
#pragma unroll
        for (int qi = 0; qi < 4; ++qi) {
            float4 qv = *(const float4*)(qp[qi] + e4 * 4);  // uniform address
            acc0[qi] += v0.x*qv.x + v0.y*qv.y + v0.z*qv.z + v0.w*qv.w;
            acc1[qi] += v1.x*qv.x + v1.y*qv.y + v1.z*qv.z + v1.w*qv.w;
            acc2[qi] += v2.x*qv.x + v2.y*qv.y + v2.z*qv.z + v2.w*qv.w;
            acc3[qi] += v3.x*qv.x + v3.y*qv.y + v3.z*qv.z + v3.w*qv.w;
        }
    }
    float di0 = 1.f / ws[WS_DNEPS + b * ND + d0];
    float di1 = 1.f / ws[WS_DNEPS + b * ND + d1];
    float di2 = 1.f / ws[WS_DNEPS + b * ND + d2];
    float di3 = 1.f / ws[WS_DNEPS + b * ND + d3];
#pragma unroll
    for (int qi = 0; qi < 4; ++qi) {
        size_t base = WS_SIM + (size_t)(b * NQ + qg + qi) * ND;
        float qn = qninv[qi];
        ws[base + d0] = acc0[qi] * qn * di0;
        ws[base + d1] = acc1[qi] * qn * di1;
        ws[base + d2] = acc2[qi] * qn * di2;
        ws[base + d3] = acc3[qi] * qn * di3;
    }
}

// ------------- kctxtop: prefix scan -> context cosine -> top-6 -------------
// grid (4, NB), 4 waves per block, one (b,q) row per wave
__global__ __launch_bounds__(256) void kctxtop(float* __restrict__ ws) {
    int b = blockIdx.y;
    int w = threadIdx.x >> 6, lane = threadIdx.x & 63;
    int q = blockIdx.x * 4 + w;
    __shared__ float P[4][ND];
    const float* simrow = ws + WS_SIM + (size_t)(b * NQ + q) * ND;
    const float* dne  = ws + WS_DNEPS + b * ND;
    const float* cinv = ws + WS_CTXINV + b * ND;
    float carry = 0.f;
    for (int c = 0; c < 13; ++c) {
        int d = c * 64 + lane;
        float v = (d < ND) ? simrow[d] * dne[d] : 0.f;  // = raw_dot/(qn+eps)
#pragma unroll
        for (int off = 1; off < 64; off <<= 1) {
            float t = __shfl_up(v, off);
            if (lane >= off) v += t;
        }
        v += carry;
        if (d < ND) P[w][d] = v;
        carry = __shfl(v, 63);
    }
    __syncthreads();
    float top[6] = {-FLT_MAX,-FLT_MAX,-FLT_MAX,-FLT_MAX,-FLT_MAX,-FLT_MAX};
    for (int c = 0; c < 13; ++c) {
        int d = c * 64 + lane;
        if (d < ND) {
            int hi_i = (d + 3 < ND) ? d + 3 : ND - 1;
            float hi = P[w][hi_i];
            float lo = (d >= 5) ? P[w][d - 5] : 0.f;
            float ctx = (hi - lo) * (1.f / 9.f) * cinv[d];
            ins6(top, ctx);
        }
    }
#pragma unroll
    for (int m = 1; m < 64; m <<= 1) {
        float o0 = __shfl_xor(top[0], m), o1 = __shfl_xor(top[1], m);
        float o2 = __shfl_xor(top[2], m), o3 = __shfl_xor(top[3], m);
        float o4 = __shfl_xor(top[4], m), o5 = __shfl_xor(top[5], m);
        ins6(top, o0); ins6(top, o1); ins6(top, o2);
        ins6(top, o3); ins6(top, o4); ins6(top, o5);
    }
    if (lane == 0) {
        float* sc = ws + WS_SCORES + (size_t)(b * NQ + q) * 13;
        sc[6] = top[0]; sc[7] = top[1]; sc[8]  = top[2];
        sc[9] = top[3]; sc[10] = top[4]; sc[11] = top[5];
    }
}

// ---------------- kconv: 3 pacrr convs + maxF + top2 over d ----------------
// grid (8, NB): 2 q per block (needs sim rows q..q+3), block 128
__global__ __launch_bounds__(128) void kconv(const float* __restrict__ c1w,
                                             const float* __restrict__ c1b,
                                             const float* __restrict__ c2w,
                                             const float* __restrict__ c2b,
                                             const float* __restrict__ c3w,
                                             const float* __restrict__ c3b,
                                             float* __restrict__ ws) {
    int b = blockIdx.y;
    int qp = blockIdx.x * 2;
    int tid = threadIdx.x;
    __shared__ float S[4][802];
    for (int idx = tid; idx < 4 * 802; idx += 128) {
        int r = idx / 802, c = idx % 802;
        int q = qp + r;
        float v = 0.f;
        if (q < NQ && c < ND) v = ws[WS_SIM + (size_t)(b * NQ + q) * ND + c];
        S[r][c] = v;
    }
    __syncthreads();
    int qi = tid & 1;
    int ds = tid >> 1;  // 0..63
    float a1[3] = {-FLT_MAX,-FLT_MAX,-FLT_MAX};
    float a2[3] = {-FLT_MAX,-FLT_MAX,-FLT_MAX};
    for (int jj = 0; jj < 13; ++jj) {
        int d = ds + jj * 64;
        if (d < ND) {
            float s00 = S[qi][d],     s01 = S[qi][d + 1],     s02 = S[qi][d + 2];
            float s10 = S[qi + 1][d], s11 = S[qi + 1][d + 1], s12 = S[qi + 1][d + 2];
            float s20 = S[qi + 2][d], s21 = S[qi + 2][d + 1], s22 = S[qi + 2][d + 2];
            float m1 = -FLT_MAX, m2 = -FLT_MAX, m3 = -FLT_MAX;
            for (int f = 0; f < 32; ++f) {   // weights: wave-uniform scalar loads
                float v1 = c1w[f] * s00 + c1b[f];
                m1 = fmaxf(m1, v1);
                float v2 = c2b[f] + c2w[f*4+0]*s00 + c2w[f*4+1]*s01
                                  + c2w[f*4+2]*s10 + c2w[f*4+3]*s11;
                m2 = fmaxf(m2, v2);
                float v3 = c3b[f] + c3w[f*9+0]*s00 + c3w[f*9+1]*s01 + c3w[f*9+2]*s02
                                  + c3w[f*9+3]*s10 + c3w[f*9+4]*s11 + c3w[f*9+5]*s12
                                  + c3w[f*9+6]*s20 + c3w[f*9+7]*s21 + c3w[f*9+8]*s22;
                m3 = fmaxf(m3, v3);
            }
            m1 = fmaxf(m1, 0.f); m2 = fmaxf(m2, 0.f); m3 = fmaxf(m3, 0.f);
            ins2(a1[0], a2[0], m1); ins2(a1[1], a2[1], m2); ins2(a1[2], a2[2], m3);
        }
    }
    // merge across lanes of same parity (same qi) within the wave
#pragma unroll
    for (int m = 2; m <= 32; m <<= 1) {
#pragma unroll
        for (int ng = 0; ng < 3; ++ng) {
            float b1v = __shfl_xor(a1[ng], m), b2v = __shfl_xor(a2[ng], m);
            merge2(a1[ng], a2[ng], b1v, b2v);
        }
    }
    __shared__ float PART[2][2][6];
    int wv = tid >> 6;
    if ((tid & 63) < 2) {
#pragma unroll
        for (int ng = 0; ng < 3; ++ng) {
            PART[wv][qi][ng * 2]     = a1[ng];
            PART[wv][qi][ng * 2 + 1] = a2[ng];
        }
    }
    __syncthreads();
    if (tid < 2) {
        float* sc = ws + WS_SCORES + (size_t)(b * NQ + qp + tid) * 13;
#pragma unroll
        for (int ng = 0; ng < 3; ++ng) {
            float x1 = PART[0][tid][ng * 2], x2 = PART[0][tid][ng * 2 + 1];
            merge2(x1, x2, PART[1][tid][ng * 2], PART[1][tid][ng * 2 + 1]);
            sc[ng * 2] = x1; sc[ng * 2 + 1] = x2;
        }
    }
}

// ---------------- kmlp: 208 -> 32 -> 32 -> 1 ----------------
__global__ __launch_bounds__(64) void kmlp(const float* __restrict__ w1,
                                           const float* __restrict__ b1,
                                           const float* __restrict__ w2,
                                           const float* __restrict__ b2,
                                           const float* __restrict__ w3,
                                           const float* __restrict__ b3,
                                           const float* __restrict__ ws,
                                           float* __restrict__ out) {
    int b = blockIdx.x, l = threadIdx.x;
    __shared__ float sc[208];
    __shared__ float h[32];
    const float* s = ws + WS_SCORES + (size_t)b * 208;
    for (int i = l; i < 208; i += 64) sc[i] = s[i];
    __syncthreads();
    int j = l & 31, half = l >> 5;
    float a = 0.f;
    int i0 = half * 104;
    for (int i = 0; i < 104; ++i) a += sc[i0 + i] * w1[(i0 + i) * 32 + j];
    a += __shfl_xor(a, 32);
    a = fmaxf(a + b1[j], 0.f);
    if (half == 0) h[j] = a;
    __syncthreads();
    float r = 0.f;
    if (half == 0) {
        float a2 = 0.f;
        for (int k = 0; k < 32; ++k) a2 += h[k] * w2[k * 32 + j];
        a2 = fmaxf(a2 + b2[j], 0.f);
        r = a2 * w3[j];
    }
#pragma unroll
    for (int m = 1; m <= 32; m <<= 1) r += __shfl_xor(r, m);
    if (l == 0) out[b] = r + b3[0];
}

extern "C" void kernel_launch(void* const* d_in, const int* in_sizes, int n_in,
                              void* d_out, int out_size, void* d_ws, size_t ws_size,
                              hipStream_t stream) {
    (void)in_sizes; (void)n_in; (void)out_size; (void)ws_size;
    const int*   qrls = (const int*)d_in[0];
    const int*   docw = (const int*)d_in[1];
    const float* emb  = (const float*)d_in[2];
    const float* idf  = (const float*)d_in[3];
    const float* c1w  = (const float*)d_in[4];
    const float* c1b  = (const float*)d_in[5];
    const float* c2w  = (const float*)d_in[6];
    const float* c2b  = (const float*)d_in[7];
    const float* c3w  = (const float*)d_in[8];
    const float* c3b  = (const float*)d_in[9];
    const float* w1   = (const float*)d_in[10];
    const float* b1   = (const float*)d_in[11];
    const float* w2   = (const float*)d_in[12];
    const float* b2   = (const float*)d_in[13];
    const float* w3   = (const float*)d_in[14];
    const float* b3   = (const float*)d_in[15];
    float* ws  = (float*)d_ws;
    float* out = (float*)d_out;

    kq<<<dim3(NB), 64, 0, stream>>>(qrls, emb, idf, ws);
    kctx<<<dim3(13, NB), 256, 0, stream>>>(docw, emb, ws);
    ksim<<<dim3(4, NB), 256, 0, stream>>>(qrls, docw, emb, ws);
    kctxtop<<<dim3(4, NB), 256, 0, stream>>>(ws);
    kconv<<<dim3(8, NB), 128, 0, stream>>>(c1w, c1b, c2w, c2b, c3w, c3b, ws);
    kmlp<<<dim3(NB), 64, 0, stream>>>(w1, b1, w2, b2, w3, b3, ws, out);
}

// Round 2
// 218.022 us; speedup vs baseline: 2.3610x; 2.3610x over previous
//
#include <hip/hip_runtime.h>
#include <float.h>
#include <math.h>

#define NB 128
#define NQ 16
#define ND 800
#define NE 300

// workspace layout (float offsets)
#define WS_SIM    0
#define WS_DNEPS  (NB*NQ*ND)              // dnorm + 1e-9        [NB][ND]
#define WS_CTXINV (WS_DNEPS + NB*ND)      // 1/(ctxnorm/9+1e-9)  [NB][ND]
#define WS_QNINV  (WS_CTXINV + NB*ND)     // 1/(qnorm+1e-9)      [NB][NQ]
#define WS_SCORES (WS_QNINV + NB*NQ)      // [NB][NQ][13]

__device__ __forceinline__ void ins6(float t[6], float v) {
    if (v > t[5]) t[5] = v;
    float a;
    if (t[5] > t[4]) { a = t[4]; t[4] = t[5]; t[5] = a; }
    if (t[4] > t[3]) { a = t[3]; t[3] = t[4]; t[4] = a; }
    if (t[3] > t[2]) { a = t[2]; t[2] = t[3]; t[3] = a; }
    if (t[2] > t[1]) { a = t[1]; t[1] = t[2]; t[2] = a; }
    if (t[1] > t[0]) { a = t[0]; t[0] = t[1]; t[1] = a; }
}

__device__ __forceinline__ void ins2(float& a1, float& a2, float v) {
    if (v > a2) a2 = v;
    if (a2 > a1) { float t = a1; a1 = a2; a2 = t; }
}

__device__ __forceinline__ void merge2(float& a1, float& a2, float b1v, float b2v) {
    float hi = fmaxf(a1, b1v), lo = fminf(a1, b1v);
    a1 = hi;
    a2 = fmaxf(lo, fmaxf(a2, b2v));
}

// sliding sum of 8 consecutive lanes (this lane .. lane+7)
__device__ __forceinline__ float slide8(float s) {
    s += __shfl_down(s, 1);
    s += __shfl_down(s, 2);
    s += __shfl_down(s, 4);
    return s;
}

// ---------------- kq: q-norm inverse + idf into scores[12] ----------------
__global__ __launch_bounds__(64) void kq(const int* __restrict__ qrls,
                                         const float* __restrict__ emb,
                                         const float* __restrict__ idf,
                                         float* __restrict__ ws) {
    int b = blockIdx.x;
    int l = threadIdx.x;
    int q = l & 15, part = l >> 4;
    int row = qrls[b * NQ + q];
    const float* p = emb + (size_t)row * NE;
    float s = 0.f;
    int e0 = part * 75;
    for (int k = 0; k < 75; ++k) { float v = p[e0 + k]; s += v * v; }
    s += __shfl_xor(s, 16);
    s += __shfl_xor(s, 32);
    if (part == 0) {
        ws[WS_QNINV + b * NQ + q] = 1.f / (sqrtf(s) + 1e-9f);
        ws[WS_SCORES + (b * NQ + q) * 13 + 12] = idf[row];
    }
}

// ------------- ksimctx: fused sim matrix + doc norm + context norm -------------
// grid (4, NB), 256 threads = 4 waves. Each wave: 64 lanes hold 64 consecutive
// doc rows (with 4-row halo each side), outputs 56 d-positions.
// Per lane: dot its row against all 16 q (scalar-loaded), own-row norm, and
// 8-row sliding window sum via shfl for the context norm.
__global__ __launch_bounds__(256) void ksimctx(const int* __restrict__ qrls,
                                               const int* __restrict__ docw,
                                               const float* __restrict__ emb,
                                               float* __restrict__ ws) {
    int b = blockIdx.y;
    int wv = (blockIdx.x << 2) + (threadIdx.x >> 6);   // 0..15 (15 used)
    int lane = threadIdx.x & 63;
    int base = wv * 56;
    int r = base - 4 + lane;
    bool rvalid = (r >= 0 && r < ND);
    const float4* dv = (const float4*)emb;  // dummy, loads guarded
    if (rvalid) dv = (const float4*)(emb + (size_t)docw[b * ND + r] * NE);

    const float4* qv[NQ];
    float qninv[NQ];
#pragma unroll
    for (int i = 0; i < NQ; ++i) {
        int row = __builtin_amdgcn_readfirstlane(qrls[b * NQ + i]);
        qv[i] = (const float4*)(emb + (size_t)row * NE);
        qninv[i] = ws[WS_QNINV + b * NQ + i];
    }

    float acc[NQ];
#pragma unroll
    for (int i = 0; i < NQ; ++i) acc[i] = 0.f;
    float sqd = 0.f, sq = 0.f;

    float4 z4; z4.x = z4.y = z4.z = z4.w = 0.f;
    float4 v = rvalid ? dv[0] : z4;
    for (int e4 = 0; e4 < 75; ++e4) {
        float4 vn = (rvalid && e4 < 74) ? dv[e4 + 1] : z4;  // prefetch
#pragma unroll
        for (int i = 0; i < NQ; ++i) {
            float4 q = qv[i][e4];                           // scalar loads
            acc[i] = fmaf(v.x, q.x, acc[i]);
            acc[i] = fmaf(v.y, q.y, acc[i]);
            acc[i] = fmaf(v.z, q.z, acc[i]);
            acc[i] = fmaf(v.w, q.w, acc[i]);
        }
        sqd = fmaf(v.x, v.x, sqd); sqd = fmaf(v.y, v.y, sqd);
        sqd = fmaf(v.z, v.z, sqd); sqd = fmaf(v.w, v.w, sqd);
        float s0 = slide8(v.x), s1 = slide8(v.y);
        float s2 = slide8(v.z), s3 = slide8(v.w);
        sq = fmaf(s0, s0, sq); sq = fmaf(s1, s1, sq);
        sq = fmaf(s2, s2, sq); sq = fmaf(s3, s3, sq);
        v = vn;
    }

    float dne_ = sqrtf(sqd) + 1e-9f;
    float dninv = 1.f / dne_;
    if (lane >= 4 && lane < 60 && r < ND) {
        ws[WS_DNEPS + b * ND + r] = dne_;
#pragma unroll
        for (int i = 0; i < NQ; ++i)
            ws[WS_SIM + (size_t)(b * NQ + i) * ND + r] = acc[i] * qninv[i] * dninv;
    }
    int dc = base + lane;
    if (lane < 56 && dc < ND)
        ws[WS_CTXINV + b * ND + dc] = 1.f / (sqrtf(sq) * (1.f / 9.f) + 1e-9f);
}

// ------------- kctxtop: prefix scan -> context cosine -> top-6 -------------
// grid (4, NB), 4 waves per block, one (b,q) row per wave
__global__ __launch_bounds__(256) void kctxtop(float* __restrict__ ws) {
    int b = blockIdx.y;
    int w = threadIdx.x >> 6, lane = threadIdx.x & 63;
    int q = blockIdx.x * 4 + w;
    __shared__ float P[4][ND];
    const float* simrow = ws + WS_SIM + (size_t)(b * NQ + q) * ND;
    const float* dne  = ws + WS_DNEPS + b * ND;
    const float* cinv = ws + WS_CTXINV + b * ND;
    float carry = 0.f;
    for (int c = 0; c < 13; ++c) {
        int d = c * 64 + lane;
        float v = (d < ND) ? simrow[d] * dne[d] : 0.f;  // = raw_dot/(qn+eps)
#pragma unroll
        for (int off = 1; off < 64; off <<= 1) {
            float t = __shfl_up(v, off);
            if (lane >= off) v += t;
        }
        v += carry;
        if (d < ND) P[w][d] = v;
        carry = __shfl(v, 63);
    }
    __syncthreads();
    float top[6] = {-FLT_MAX,-FLT_MAX,-FLT_MAX,-FLT_MAX,-FLT_MAX,-FLT_MAX};
    for (int c = 0; c < 13; ++c) {
        int d = c * 64 + lane;
        if (d < ND) {
            int hi_i = (d + 3 < ND) ? d + 3 : ND - 1;
            float hi = P[w][hi_i];
            float lo = (d >= 5) ? P[w][d - 5] : 0.f;
            float ctx = (hi - lo) * (1.f / 9.f) * cinv[d];
            ins6(top, ctx);
        }
    }
#pragma unroll
    for (int m = 1; m < 64; m <<= 1) {
        float o0 = __shfl_xor(top[0], m), o1 = __shfl_xor(top[1], m);
        float o2 = __shfl_xor(top[2], m), o3 = __shfl_xor(top[3], m);
        float o4 = __shfl_xor(top[4], m), o5 = __shfl_xor(top[5], m);
        ins6(top, o0); ins6(top, o1); ins6(top, o2);
        ins6(top, o3); ins6(top, o4); ins6(top, o5);
    }
    if (lane == 0) {
        float* sc = ws + WS_SCORES + (size_t)(b * NQ + q) * 13;
        sc[6] = top[0]; sc[7] = top[1]; sc[8]  = top[2];
        sc[9] = top[3]; sc[10] = top[4]; sc[11] = top[5];
    }
}

// ---------------- kconv: 3 pacrr convs + maxF + top2 over d ----------------
// grid (8, NB): 2 q per block (needs sim rows q..q+3), block 128
__global__ __launch_bounds__(128) void kconv(const float* __restrict__ c1w,
                                             const float* __restrict__ c1b,
                                             const float* __restrict__ c2w,
                                             const float* __restrict__ c2b,
                                             const float* __restrict__ c3w,
                                             const float* __restrict__ c3b,
                                             float* __restrict__ ws) {
    int b = blockIdx.y;
    int qp = blockIdx.x * 2;
    int tid = threadIdx.x;
    __shared__ float S[4][802];
    for (int idx = tid; idx < 4 * 802; idx += 128) {
        int r = idx / 802, c = idx % 802;
        int q = qp + r;
        float v = 0.f;
        if (q < NQ && c < ND) v = ws[WS_SIM + (size_t)(b * NQ + q) * ND + c];
        S[r][c] = v;
    }
    __syncthreads();
    int qi = tid & 1;
    int ds = tid >> 1;  // 0..63
    float a1[3] = {-FLT_MAX,-FLT_MAX,-FLT_MAX};
    float a2[3] = {-FLT_MAX,-FLT_MAX,-FLT_MAX};
    for (int jj = 0; jj < 13; ++jj) {
        int d = ds + jj * 64;
        if (d < ND) {
            float s00 = S[qi][d],     s01 = S[qi][d + 1],     s02 = S[qi][d + 2];
            float s10 = S[qi + 1][d], s11 = S[qi + 1][d + 1], s12 = S[qi + 1][d + 2];
            float s20 = S[qi + 2][d], s21 = S[qi + 2][d + 1], s22 = S[qi + 2][d + 2];
            float m1 = -FLT_MAX, m2 = -FLT_MAX, m3 = -FLT_MAX;
            for (int f = 0; f < 32; ++f) {   // weights: wave-uniform scalar loads
                float v1 = c1w[f] * s00 + c1b[f];
                m1 = fmaxf(m1, v1);
                float v2 = c2b[f] + c2w[f*4+0]*s00 + c2w[f*4+1]*s01
                                  + c2w[f*4+2]*s10 + c2w[f*4+3]*s11;
                m2 = fmaxf(m2, v2);
                float v3 = c3b[f] + c3w[f*9+0]*s00 + c3w[f*9+1]*s01 + c3w[f*9+2]*s02
                                  + c3w[f*9+3]*s10 + c3w[f*9+4]*s11 + c3w[f*9+5]*s12
                                  + c3w[f*9+6]*s20 + c3w[f*9+7]*s21 + c3w[f*9+8]*s22;
                m3 = fmaxf(m3, v3);
            }
            m1 = fmaxf(m1, 0.f); m2 = fmaxf(m2, 0.f); m3 = fmaxf(m3, 0.f);
            ins2(a1[0], a2[0], m1); ins2(a1[1], a2[1], m2); ins2(a1[2], a2[2], m3);
        }
    }
#pragma unroll
    for (int m = 2; m <= 32; m <<= 1) {
#pragma unroll
        for (int ng = 0; ng < 3; ++ng) {
            float b1v = __shfl_xor(a1[ng], m), b2v = __shfl_xor(a2[ng], m);
            merge2(a1[ng], a2[ng], b1v, b2v);
        }
    }
    __shared__ float PART[2][2][6];
    int wv = tid >> 6;
    if ((tid & 63) < 2) {
#pragma unroll
        for (int ng = 0; ng < 3; ++ng) {
            PART[wv][qi][ng * 2]     = a1[ng];
            PART[wv][qi][ng * 2 + 1] = a2[ng];
        }
    }
    __syncthreads();
    if (tid < 2) {
        float* sc = ws + WS_SCORES + (size_t)(b * NQ + qp + tid) * 13;
#pragma unroll
        for (int ng = 0; ng < 3; ++ng) {
            float x1 = PART[0][tid][ng * 2], x2 = PART[0][tid][ng * 2 + 1];
            merge2(x1, x2, PART[1][tid][ng * 2], PART[1][tid][ng * 2 + 1]);
            sc[ng * 2] = x1; sc[ng * 2 + 1] = x2;
        }
    }
}

// ---------------- kmlp: 208 -> 32 -> 32 -> 1 ----------------
__global__ __launch_bounds__(64) void kmlp(const float* __restrict__ w1,
                                           const float* __restrict__ b1,
                                           const float* __restrict__ w2,
                                           const float* __restrict__ b2,
                                           const float* __restrict__ w3,
                                           const float* __restrict__ b3,
                                           const float* __restrict__ ws,
                                           float* __restrict__ out) {
    int b = blockIdx.x, l = threadIdx.x;
    __shared__ float sc[208];
    __shared__ float h[32];
    const float* s = ws + WS_SCORES + (size_t)b * 208;
    for (int i = l; i < 208; i += 64) sc[i] = s[i];
    __syncthreads();
    int j = l & 31, half = l >> 5;
    float a = 0.f;
    int i0 = half * 104;
    for (int i = 0; i < 104; ++i) a += sc[i0 + i] * w1[(i0 + i) * 32 + j];
    a += __shfl_xor(a, 32);
    a = fmaxf(a + b1[j], 0.f);
    if (half == 0) h[j] = a;
    __syncthreads();
    float r = 0.f;
    if (half == 0) {
        float a2 = 0.f;
        for (int k = 0; k < 32; ++k) a2 += h[k] * w2[k * 32 + j];
        a2 = fmaxf(a2 + b2[j], 0.f);
        r = a2 * w3[j];
    }
#pragma unroll
    for (int m = 1; m <= 32; m <<= 1) r += __shfl_xor(r, m);
    if (l == 0) out[b] = r + b3[0];
}

extern "C" void kernel_launch(void* const* d_in, const int* in_sizes, int n_in,
                              void* d_out, int out_size, void* d_ws, size_t ws_size,
                              hipStream_t stream) {
    (void)in_sizes; (void)n_in; (void)out_size; (void)ws_size;
    const int*   qrls = (const int*)d_in[0];
    const int*   docw = (const int*)d_in[1];
    const float* emb  = (const float*)d_in[2];
    const float* idf  = (const float*)d_in[3];
    const float* c1w  = (const float*)d_in[4];
    const float* c1b  = (const float*)d_in[5];
    const float* c2w  = (const float*)d_in[6];
    const float* c2b  = (const float*)d_in[7];
    const float* c3w  = (const float*)d_in[8];
    const float* c3b  = (const float*)d_in[9];
    const float* w1   = (const float*)d_in[10];
    const float* b1   = (const float*)d_in[11];
    const float* w2   = (const float*)d_in[12];
    const float* b2   = (const float*)d_in[13];
    const float* w3   = (const float*)d_in[14];
    const float* b3   = (const float*)d_in[15];
    float* ws  = (float*)d_ws;
    float* out = (float*)d_out;

    kq<<<dim3(NB), 64, 0, stream>>>(qrls, emb, idf, ws);
    ksimctx<<<dim3(4, NB), 256, 0, stream>>>(qrls, docw, emb, ws);
    kctxtop<<<dim3(4, NB), 256, 0, stream>>>(ws);
    kconv<<<dim3(8, NB), 128, 0, stream>>>(c1w, c1b, c2w, c2b, c3w, c3b, ws);
    kmlp<<<dim3(NB), 64, 0, stream>>>(w1, b1, w2, b2, w3, b3, ws, out);
}

// Round 3
// 179.006 us; speedup vs baseline: 2.8756x; 1.2180x over previous
//
#include <hip/hip_runtime.h>
#include <float.h>
#include <math.h>

#define NB 128
#define NQ 16
#define ND 800
#define NE 300

// workspace layout (float offsets)
#define WS_SIM    0
#define WS_DNEPS  (NB*NQ*ND)              // dnorm + 1e-9        [NB][ND]
#define WS_CTXINV (WS_DNEPS + NB*ND)      // 1/(ctxnorm/9+1e-9)  [NB][ND]
#define WS_QNINV  (WS_CTXINV + NB*ND)     // 1/(qnorm+1e-9)      [NB][NQ]
#define WS_SCORES (WS_QNINV + NB*NQ)      // [NB][NQ][13]
#define WS_QT     (WS_SCORES + NB*NQ*13)  // transposed q: [NB][75][16] float4

__device__ __forceinline__ void ins6(float t[6], float v) {
    if (v > t[5]) t[5] = v;
    float a;
    if (t[5] > t[4]) { a = t[4]; t[4] = t[5]; t[5] = a; }
    if (t[4] > t[3]) { a = t[3]; t[3] = t[4]; t[4] = a; }
    if (t[3] > t[2]) { a = t[2]; t[2] = t[3]; t[3] = a; }
    if (t[2] > t[1]) { a = t[1]; t[1] = t[2]; t[2] = a; }
    if (t[1] > t[0]) { a = t[0]; t[0] = t[1]; t[1] = a; }
}

__device__ __forceinline__ void ins2(float& a1, float& a2, float v) {
    if (v > a2) a2 = v;
    if (a2 > a1) { float t = a1; a1 = a2; a2 = t; }
}

__device__ __forceinline__ void merge2(float& a1, float& a2, float b1v, float b2v) {
    float hi = fmaxf(a1, b1v), lo = fminf(a1, b1v);
    a1 = hi;
    a2 = fmaxf(lo, fmaxf(a2, b2v));
}

// sliding sum of 8 consecutive lanes (this lane .. lane+7)
__device__ __forceinline__ float slide8(float s) {
    s += __shfl_down(s, 1);
    s += __shfl_down(s, 2);
    s += __shfl_down(s, 4);
    return s;
}

// ------- kq: q transpose into WS_QT + q-norm inverse + idf -------
__global__ __launch_bounds__(256) void kq(const int* __restrict__ qrls,
                                          const float* __restrict__ emb,
                                          const float* __restrict__ idf,
                                          float* __restrict__ ws) {
    int b = blockIdx.x;
    int tid = threadIdx.x;
    // phase A: transpose q rows into [e4][q] float4 layout (1200 float4s)
    const float4* emb4 = (const float4*)emb;
    float4* qt = ((float4*)(ws + WS_QT)) + (size_t)b * 75 * 16;
    for (int idx = tid; idx < 75 * 16; idx += 256) {
        int e4 = idx >> 4, q = idx & 15;
        int row = qrls[b * NQ + q];
        qt[idx] = emb4[(size_t)row * 75 + e4];
    }
    // phase B: q norms + idf (wave 0 only)
    if (tid < 64) {
        int q = tid & 15, part = tid >> 4;
        int row = qrls[b * NQ + q];
        const float* p = emb + (size_t)row * NE;
        float s = 0.f;
        int e0 = part * 75;
        for (int k = 0; k < 75; ++k) { float v = p[e0 + k]; s += v * v; }
        s += __shfl_xor(s, 16);
        s += __shfl_xor(s, 32);
        if (part == 0) {
            ws[WS_QNINV + b * NQ + q] = 1.f / (sqrtf(s) + 1e-9f);
            ws[WS_SCORES + (b * NQ + q) * 13 + 12] = idf[row];
        }
    }
}

// ------- ksim8: fused sim (8 q per wave) + doc norm + context norm -------
// grid (15, NB), 128 threads = 2 waves over the SAME 64-row chunk:
// wave 0 = q0..7 (+ ctx norm via slide8), wave 1 = q8..15.
// q operands come from the transposed WS_QT buffer via scalar loads
// (128 contiguous bytes per iteration per wave), explicitly prefetched.
__global__ __launch_bounds__(128) void ksim8(const int* __restrict__ docw,
                                             const float* __restrict__ emb,
                                             float* __restrict__ ws) {
    int b = blockIdx.y;
    int chunk = blockIdx.x;                  // 0..14
    int wv = __builtin_amdgcn_readfirstlane(threadIdx.x >> 6);  // 0 or 1, uniform
    int lane = threadIdx.x & 63;
    int base = chunk * 56;
    int r = base - 4 + lane;
    bool rvalid = (r >= 0 && r < ND);
    const float4* dv = (const float4*)emb;
    if (rvalid) dv = (const float4*)(emb + (size_t)docw[b * ND + r] * NE);

    const float4* qt = ((const float4*)(ws + WS_QT)) + (size_t)b * 75 * 16 + wv * 8;
    float qninv[8];
#pragma unroll
    for (int i = 0; i < 8; ++i) qninv[i] = ws[WS_QNINV + b * NQ + wv * 8 + i];

    float acc[8];
#pragma unroll
    for (int i = 0; i < 8; ++i) acc[i] = 0.f;
    float sqd = 0.f, sq = 0.f;

    float4 z4; z4.x = z4.y = z4.z = z4.w = 0.f;
    float4 v = rvalid ? dv[0] : z4;
    float4 qb[8];
#pragma unroll
    for (int i = 0; i < 8; ++i) qb[i] = qt[i];

    for (int e4 = 0; e4 < 75; ++e4) {
        int e4n = (e4 < 74) ? e4 + 1 : 74;
        // prefetch next iteration's operands
        float4 vn = (rvalid && e4 < 74) ? dv[e4 + 1] : z4;
        float4 qn[8];
        const float4* qnp = qt + (size_t)e4n * 16;
#pragma unroll
        for (int i = 0; i < 8; ++i) qn[i] = qnp[i];

#pragma unroll
        for (int i = 0; i < 8; ++i) {
            acc[i] = fmaf(v.x, qb[i].x, acc[i]);
            acc[i] = fmaf(v.y, qb[i].y, acc[i]);
            acc[i] = fmaf(v.z, qb[i].z, acc[i]);
            acc[i] = fmaf(v.w, qb[i].w, acc[i]);
        }
        sqd = fmaf(v.x, v.x, sqd); sqd = fmaf(v.y, v.y, sqd);
        sqd = fmaf(v.z, v.z, sqd); sqd = fmaf(v.w, v.w, sqd);
        if (wv == 0) {
            float s0 = slide8(v.x), s1 = slide8(v.y);
            float s2 = slide8(v.z), s3 = slide8(v.w);
            sq = fmaf(s0, s0, sq); sq = fmaf(s1, s1, sq);
            sq = fmaf(s2, s2, sq); sq = fmaf(s3, s3, sq);
        }
#pragma unroll
        for (int i = 0; i < 8; ++i) qb[i] = qn[i];
        v = vn;
    }

    float dne_ = sqrtf(sqd) + 1e-9f;
    float dninv = 1.f / dne_;
    if (lane >= 4 && lane < 60 && r < ND) {
        if (wv == 0) ws[WS_DNEPS + b * ND + r] = dne_;
#pragma unroll
        for (int i = 0; i < 8; ++i)
            ws[WS_SIM + (size_t)(b * NQ + wv * 8 + i) * ND + r] = acc[i] * qninv[i] * dninv;
    }
    int dc = base + lane;
    if (wv == 0 && lane < 56 && dc < ND)
        ws[WS_CTXINV + b * ND + dc] = 1.f / (sqrtf(sq) * (1.f / 9.f) + 1e-9f);
}

// ------- kctxtop: prefix scan -> context cosine -> top-6 -------
__global__ __launch_bounds__(256) void kctxtop(float* __restrict__ ws) {
    int b = blockIdx.y;
    int w = threadIdx.x >> 6, lane = threadIdx.x & 63;
    int q = blockIdx.x * 4 + w;
    __shared__ float P[4][ND];
    const float* simrow = ws + WS_SIM + (size_t)(b * NQ + q) * ND;
    const float* dne  = ws + WS_DNEPS + b * ND;
    const float* cinv = ws + WS_CTXINV + b * ND;
    float carry = 0.f;
    for (int c = 0; c < 13; ++c) {
        int d = c * 64 + lane;
        float v = (d < ND) ? simrow[d] * dne[d] : 0.f;
#pragma unroll
        for (int off = 1; off < 64; off <<= 1) {
            float t = __shfl_up(v, off);
            if (lane >= off) v += t;
        }
        v += carry;
        if (d < ND) P[w][d] = v;
        carry = __shfl(v, 63);
    }
    __syncthreads();
    float top[6] = {-FLT_MAX,-FLT_MAX,-FLT_MAX,-FLT_MAX,-FLT_MAX,-FLT_MAX};
    for (int c = 0; c < 13; ++c) {
        int d = c * 64 + lane;
        if (d < ND) {
            int hi_i = (d + 3 < ND) ? d + 3 : ND - 1;
            float hi = P[w][hi_i];
            float lo = (d >= 5) ? P[w][d - 5] : 0.f;
            float ctx = (hi - lo) * (1.f / 9.f) * cinv[d];
            ins6(top, ctx);
        }
    }
#pragma unroll
    for (int m = 1; m < 64; m <<= 1) {
        float o0 = __shfl_xor(top[0], m), o1 = __shfl_xor(top[1], m);
        float o2 = __shfl_xor(top[2], m), o3 = __shfl_xor(top[3], m);
        float o4 = __shfl_xor(top[4], m), o5 = __shfl_xor(top[5], m);
        ins6(top, o0); ins6(top, o1); ins6(top, o2);
        ins6(top, o3); ins6(top, o4); ins6(top, o5);
    }
    if (lane == 0) {
        float* sc = ws + WS_SCORES + (size_t)(b * NQ + q) * 13;
        sc[6] = top[0]; sc[7] = top[1]; sc[8]  = top[2];
        sc[9] = top[3]; sc[10] = top[4]; sc[11] = top[5];
    }
}

// ------- kconv: 3 pacrr convs + maxF + top2 over d -------
__global__ __launch_bounds__(128) void kconv(const float* __restrict__ c1w,
                                             const float* __restrict__ c1b,
                                             const float* __restrict__ c2w,
                                             const float* __restrict__ c2b,
                                             const float* __restrict__ c3w,
                                             const float* __restrict__ c3b,
                                             float* __restrict__ ws) {
    int b = blockIdx.y;
    int qp = blockIdx.x * 2;
    int tid = threadIdx.x;
    __shared__ float S[4][802];
    for (int idx = tid; idx < 4 * 802; idx += 128) {
        int r = idx / 802, c = idx % 802;
        int q = qp + r;
        float v = 0.f;
        if (q < NQ && c < ND) v = ws[WS_SIM + (size_t)(b * NQ + q) * ND + c];
        S[r][c] = v;
    }
    __syncthreads();
    int qi = tid & 1;
    int ds = tid >> 1;
    float a1[3] = {-FLT_MAX,-FLT_MAX,-FLT_MAX};
    float a2[3] = {-FLT_MAX,-FLT_MAX,-FLT_MAX};
    for (int jj = 0; jj < 13; ++jj) {
        int d = ds + jj * 64;
        if (d < ND) {
            float s00 = S[qi][d],     s01 = S[qi][d + 1],     s02 = S[qi][d + 2];
            float s10 = S[qi + 1][d], s11 = S[qi + 1][d + 1], s12 = S[qi + 1][d + 2];
            float s20 = S[qi + 2][d], s21 = S[qi + 2][d + 1], s22 = S[qi + 2][d + 2];
            float m1 = -FLT_MAX, m2 = -FLT_MAX, m3 = -FLT_MAX;
            for (int f = 0; f < 32; ++f) {
                float v1 = c1w[f] * s00 + c1b[f];
                m1 = fmaxf(m1, v1);
                float v2 = c2b[f] + c2w[f*4+0]*s00 + c2w[f*4+1]*s01
                                  + c2w[f*4+2]*s10 + c2w[f*4+3]*s11;
                m2 = fmaxf(m2, v2);
                float v3 = c3b[f] + c3w[f*9+0]*s00 + c3w[f*9+1]*s01 + c3w[f*9+2]*s02
                                  + c3w[f*9+3]*s10 + c3w[f*9+4]*s11 + c3w[f*9+5]*s12
                                  + c3w[f*9+6]*s20 + c3w[f*9+7]*s21 + c3w[f*9+8]*s22;
                m3 = fmaxf(m3, v3);
            }
            m1 = fmaxf(m1, 0.f); m2 = fmaxf(m2, 0.f); m3 = fmaxf(m3, 0.f);
            ins2(a1[0], a2[0], m1); ins2(a1[1], a2[1], m2); ins2(a1[2], a2[2], m3);
        }
    }
#pragma unroll
    for (int m = 2; m <= 32; m <<= 1) {
#pragma unroll
        for (int ng = 0; ng < 3; ++ng) {
            float b1v = __shfl_xor(a1[ng], m), b2v = __shfl_xor(a2[ng], m);
            merge2(a1[ng], a2[ng], b1v, b2v);
        }
    }
    __shared__ float PART[2][2][6];
    int wv = tid >> 6;
    if ((tid & 63) < 2) {
#pragma unroll
        for (int ng = 0; ng < 3; ++ng) {
            PART[wv][qi][ng * 2]     = a1[ng];
            PART[wv][qi][ng * 2 + 1] = a2[ng];
        }
    }
    __syncthreads();
    if (tid < 2) {
        float* sc = ws + WS_SCORES + (size_t)(b * NQ + qp + tid) * 13;
#pragma unroll
        for (int ng = 0; ng < 3; ++ng) {
            float x1 = PART[0][tid][ng * 2], x2 = PART[0][tid][ng * 2 + 1];
            merge2(x1, x2, PART[1][tid][ng * 2], PART[1][tid][ng * 2 + 1]);
            sc[ng * 2] = x1; sc[ng * 2 + 1] = x2;
        }
    }
}

// ------- kmlp: 208 -> 32 -> 32 -> 1 -------
__global__ __launch_bounds__(64) void kmlp(const float* __restrict__ w1,
                                           const float* __restrict__ b1,
                                           const float* __restrict__ w2,
                                           const float* __restrict__ b2,
                                           const float* __restrict__ w3,
                                           const float* __restrict__ b3,
                                           const float* __restrict__ ws,
                                           float* __restrict__ out) {
    int b = blockIdx.x, l = threadIdx.x;
    __shared__ float sc[208];
    __shared__ float h[32];
    const float* s = ws + WS_SCORES + (size_t)b * 208;
    for (int i = l; i < 208; i += 64) sc[i] = s[i];
    __syncthreads();
    int j = l & 31, half = l >> 5;
    float a = 0.f;
    int i0 = half * 104;
    for (int i = 0; i < 104; ++i) a += sc[i0 + i] * w1[(i0 + i) * 32 + j];
    a += __shfl_xor(a, 32);
    a = fmaxf(a + b1[j], 0.f);
    if (half == 0) h[j] = a;
    __syncthreads();
    float r = 0.f;
    if (half == 0) {
        float a2 = 0.f;
        for (int k = 0; k < 32; ++k) a2 += h[k] * w2[k * 32 + j];
        a2 = fmaxf(a2 + b2[j], 0.f);
        r = a2 * w3[j];
    }
#pragma unroll
    for (int m = 1; m <= 32; m <<= 1) r += __shfl_xor(r, m);
    if (l == 0) out[b] = r + b3[0];
}

extern "C" void kernel_launch(void* const* d_in, const int* in_sizes, int n_in,
                              void* d_out, int out_size, void* d_ws, size_t ws_size,
                              hipStream_t stream) {
    (void)in_sizes; (void)n_in; (void)out_size; (void)ws_size;
    const int*   qrls = (const int*)d_in[0];
    const int*   docw = (const int*)d_in[1];
    const float* emb  = (const float*)d_in[2];
    const float* idf  = (const float*)d_in[3];
    const float* c1w  = (const float*)d_in[4];
    const float* c1b  = (const float*)d_in[5];
    const float* c2w  = (const float*)d_in[6];
    const float* c2b  = (const float*)d_in[7];
    const float* c3w  = (const float*)d_in[8];
    const float* c3b  = (const float*)d_in[9];
    const float* w1   = (const float*)d_in[10];
    const float* b1   = (const float*)d_in[11];
    const float* w2   = (const float*)d_in[12];
    const float* b2   = (const float*)d_in[13];
    const float* w3   = (const float*)d_in[14];
    const float* b3   = (const float*)d_in[15];
    float* ws  = (float*)d_ws;
    float* out = (float*)d_out;

    kq<<<dim3(NB), 256, 0, stream>>>(qrls, emb, idf, ws);
    ksim8<<<dim3(15, NB), 128, 0, stream>>>(docw, emb, ws);
    kctxtop<<<dim3(4, NB), 256, 0, stream>>>(ws);
    kconv<<<dim3(8, NB), 128, 0, stream>>>(c1w, c1b, c2w, c2b, c3w, c3b, ws);
    kmlp<<<dim3(NB), 64, 0, stream>>>(w1, b1, w2, b2, w3, b3, ws, out);
}

// Round 4
// 177.373 us; speedup vs baseline: 2.9020x; 1.0092x over previous
//
#include <hip/hip_runtime.h>
#include <float.h>
#include <math.h>

#define NB 128
#define NQ 16
#define ND 800
#define NE 300

// workspace layout (float offsets). All regions written every call.
#define WS_SIM    0                        // [NB][NQ][ND] raw dots (= cosine, unit rows)
#define WS_CTXINV (NB*NQ*ND)               // [NB][ND] 1/(||ctx||+1e-9)
#define WS_SCORES (WS_CTXINV + NB*ND)      // [NB][NQ][13] (slots 6..12 used)
#define WS_QT     (WS_SCORES + NB*NQ*13)   // [NB][75][16] float4 (q transposed)
#define WS_C2     (WS_QT + NB*75*16*4)     // [NB][NQ][3][4 strips][2] partial top2

__device__ __forceinline__ void ins6(float t[6], float v) {
    if (v > t[5]) t[5] = v;
    float a;
    if (t[5] > t[4]) { a = t[4]; t[4] = t[5]; t[5] = a; }
    if (t[4] > t[3]) { a = t[3]; t[3] = t[4]; t[4] = a; }
    if (t[3] > t[2]) { a = t[2]; t[2] = t[3]; t[3] = a; }
    if (t[2] > t[1]) { a = t[1]; t[1] = t[2]; t[2] = a; }
    if (t[1] > t[0]) { a = t[0]; t[0] = t[1]; t[1] = a; }
}

__device__ __forceinline__ void ins2(float& a1, float& a2, float v) {
    if (v > a2) a2 = v;
    if (a2 > a1) { float t = a1; a1 = a2; a2 = t; }
}

__device__ __forceinline__ void merge2(float& a1, float& a2, float b1v, float b2v) {
    float hi = fmaxf(a1, b1v), lo = fminf(a1, b1v);
    a1 = hi;
    a2 = fmaxf(lo, fmaxf(a2, b2v));
}

// sliding sum of 8 consecutive lanes (this lane .. lane+7)
__device__ __forceinline__ float slide8(float s) {
    s += __shfl_down(s, 1);
    s += __shfl_down(s, 2);
    s += __shfl_down(s, 4);
    return s;
}

// ------- kq: q transpose into WS_QT + idf (norms not needed: unit rows) -------
__global__ __launch_bounds__(256) void kq(const int* __restrict__ qrls,
                                          const float* __restrict__ emb,
                                          const float* __restrict__ idf,
                                          float* __restrict__ ws) {
    int b = blockIdx.x;
    int tid = threadIdx.x;
    const float4* emb4 = (const float4*)emb;
    float4* qt = ((float4*)(ws + WS_QT)) + (size_t)b * 1200;
    for (int idx = tid; idx < 1200; idx += 256) {
        int e4 = idx >> 4, q = idx & 15;
        int row = qrls[b * NQ + q];
        qt[idx] = emb4[(size_t)row * 75 + e4];
    }
    if (tid < NQ) {
        int row = qrls[b * NQ + tid];
        ws[WS_SCORES + (b * NQ + tid) * 13 + 12] = idf[row];
    }
}

// ------- ksim: sim dots (8 q per wave, 2 chunks per wave) + context norm -------
// grid (4, NB), 256 thr = 4 waves. Wave wv: qh=wv&1 (q-half), cp=wv>>1.
// Chunks cA=bx*4+cp*2, cB=cA+1 (15 chunks of 56 outputs, 4-row halo each side).
// q operands broadcast from LDS (uniform ds_read_b128), doc rows per-lane global.
__global__ __launch_bounds__(256) void ksim(const int* __restrict__ docw,
                                            const float* __restrict__ emb,
                                            float* __restrict__ ws) {
    int b = blockIdx.y;
    __shared__ float4 qlds[1200];
    const float4* qtg = ((const float4*)(ws + WS_QT)) + (size_t)b * 1200;
    for (int i = threadIdx.x; i < 1200; i += 256) qlds[i] = qtg[i];
    __syncthreads();

    int wv = threadIdx.x >> 6, lane = threadIdx.x & 63;
    int qh = wv & 1, cp = wv >> 1;
    int cA = blockIdx.x * 4 + cp * 2, cB = cA + 1;
    bool okB = (cB < 15);                    // cA is always <15
    int rA = cA * 56 - 4 + lane;
    int rB = cB * 56 - 4 + lane;
    bool vAok = (rA >= 0 && rA < ND);
    bool vBok = okB && (rB >= 0 && rB < ND);
    const float4* dvA = (const float4*)emb;
    const float4* dvB = (const float4*)emb;
    if (vAok) dvA = (const float4*)(emb + (size_t)docw[b * ND + rA] * NE);
    if (vBok) dvB = (const float4*)(emb + (size_t)docw[b * ND + rB] * NE);

    float accA[8], accB[8];
#pragma unroll
    for (int i = 0; i < 8; ++i) { accA[i] = 0.f; accB[i] = 0.f; }
    float sqA = 0.f, sqB = 0.f;

    float4 z4; z4.x = z4.y = z4.z = z4.w = 0.f;
    float4 vA = vAok ? dvA[0] : z4;
    float4 vB = vBok ? dvB[0] : z4;

    for (int e4 = 0; e4 < 75; ++e4) {
        float4 vAn = (vAok && e4 < 74) ? dvA[e4 + 1] : z4;
        float4 vBn = (vBok && e4 < 74) ? dvB[e4 + 1] : z4;
        float4 qb[8];
#pragma unroll
        for (int i = 0; i < 8; ++i) qb[i] = qlds[e4 * 16 + qh * 8 + i];  // broadcast
#pragma unroll
        for (int i = 0; i < 8; ++i) {
            accA[i] = fmaf(vA.x, qb[i].x, accA[i]);
            accA[i] = fmaf(vA.y, qb[i].y, accA[i]);
            accA[i] = fmaf(vA.z, qb[i].z, accA[i]);
            accA[i] = fmaf(vA.w, qb[i].w, accA[i]);
            accB[i] = fmaf(vB.x, qb[i].x, accB[i]);
            accB[i] = fmaf(vB.y, qb[i].y, accB[i]);
            accB[i] = fmaf(vB.z, qb[i].z, accB[i]);
            accB[i] = fmaf(vB.w, qb[i].w, accB[i]);
        }
        if (qh == 0) {   // wave-uniform branch: context-norm slides
            float s0 = slide8(vA.x), s1 = slide8(vA.y);
            float s2 = slide8(vA.z), s3 = slide8(vA.w);
            sqA = fmaf(s0, s0, sqA); sqA = fmaf(s1, s1, sqA);
            sqA = fmaf(s2, s2, sqA); sqA = fmaf(s3, s3, sqA);
            float t0 = slide8(vB.x), t1 = slide8(vB.y);
            float t2 = slide8(vB.z), t3 = slide8(vB.w);
            sqB = fmaf(t0, t0, sqB); sqB = fmaf(t1, t1, sqB);
            sqB = fmaf(t2, t2, sqB); sqB = fmaf(t3, t3, sqB);
        }
        vA = vAn; vB = vBn;
    }

    if (lane >= 4 && lane < 60) {
        if (rA < ND) {
#pragma unroll
            for (int i = 0; i < 8; ++i)
                ws[WS_SIM + (size_t)(b * NQ + qh * 8 + i) * ND + rA] = accA[i];
        }
        if (okB && rB < ND) {
#pragma unroll
            for (int i = 0; i < 8; ++i)
                ws[WS_SIM + (size_t)(b * NQ + qh * 8 + i) * ND + rB] = accB[i];
        }
    }
    if (qh == 0 && lane < 56) {
        int dA = cA * 56 + lane, dB = cB * 56 + lane;
        if (dA < ND)
            ws[WS_CTXINV + b * ND + dA] = 1.f / (sqrtf(sqA) * (1.f / 9.f) + 1e-9f);
        if (okB && dB < ND)
            ws[WS_CTXINV + b * ND + dB] = 1.f / (sqrtf(sqB) * (1.f / 9.f) + 1e-9f);
    }
}

// ------- kctxtop: prefix scan of raw dots -> context cosine -> top-6 -------
__global__ __launch_bounds__(256) void kctxtop(float* __restrict__ ws) {
    int b = blockIdx.y;
    int w = threadIdx.x >> 6, lane = threadIdx.x & 63;
    int q = blockIdx.x * 4 + w;
    __shared__ float P[4][ND];
    const float* simrow = ws + WS_SIM + (size_t)(b * NQ + q) * ND;
    const float* cinv = ws + WS_CTXINV + b * ND;
    float carry = 0.f;
    for (int c = 0; c < 13; ++c) {
        int d = c * 64 + lane;
        float v = (d < ND) ? simrow[d] : 0.f;
#pragma unroll
        for (int off = 1; off < 64; off <<= 1) {
            float t = __shfl_up(v, off);
            if (lane >= off) v += t;
        }
        v += carry;
        if (d < ND) P[w][d] = v;
        carry = __shfl(v, 63);
    }
    __syncthreads();
    float top[6] = {-FLT_MAX,-FLT_MAX,-FLT_MAX,-FLT_MAX,-FLT_MAX,-FLT_MAX};
    for (int c = 0; c < 13; ++c) {
        int d = c * 64 + lane;
        if (d < ND) {
            int hi_i = (d + 3 < ND) ? d + 3 : ND - 1;
            float hi = P[w][hi_i];
            float lo = (d >= 5) ? P[w][d - 5] : 0.f;
            float ctx = (hi - lo) * (1.f / 9.f) * cinv[d];
            ins6(top, ctx);
        }
    }
#pragma unroll
    for (int m = 1; m < 64; m <<= 1) {
        float o0 = __shfl_xor(top[0], m), o1 = __shfl_xor(top[1], m);
        float o2 = __shfl_xor(top[2], m), o3 = __shfl_xor(top[3], m);
        float o4 = __shfl_xor(top[4], m), o5 = __shfl_xor(top[5], m);
        ins6(top, o0); ins6(top, o1); ins6(top, o2);
        ins6(top, o3); ins6(top, o4); ins6(top, o5);
    }
    if (lane == 0) {
        float* sc = ws + WS_SCORES + (size_t)(b * NQ + q) * 13;
        sc[6] = top[0]; sc[7] = top[1]; sc[8]  = top[2];
        sc[9] = top[3]; sc[10] = top[4]; sc[11] = top[5];
    }
}

// ------- kconv: all 16 q, 200-d strip per block; partial top2 -> WS_C2 -------
__global__ __launch_bounds__(256) void kconv(const float* __restrict__ c1w,
                                             const float* __restrict__ c1b,
                                             const float* __restrict__ c2w,
                                             const float* __restrict__ c2b,
                                             const float* __restrict__ c3w,
                                             const float* __restrict__ c3b,
                                             float* __restrict__ ws) {
    int b = blockIdx.y;
    int strip = blockIdx.x;
    int c0 = strip * 200;
    int tid = threadIdx.x;
    __shared__ float S[18][204];   // rows 16,17 zero-padded; 2-col halo
    for (int idx = tid; idx < 18 * 202; idx += 256) {
        int row = idx / 202, col = idx % 202;
        int c = c0 + col;
        float v = 0.f;
        if (row < NQ && c < ND) v = ws[WS_SIM + (size_t)(b * NQ + row) * ND + c];
        S[row][col] = v;
    }
    __syncthreads();
    int q = tid & 15, dg = tid >> 4;   // 16 q x 16 d-groups
    float a1[3] = {-FLT_MAX,-FLT_MAX,-FLT_MAX};
    float a2[3] = {-FLT_MAX,-FLT_MAX,-FLT_MAX};
    for (int j = 0; j < 13; ++j) {
        int dl = dg + j * 16;
        if (dl < 200 && c0 + dl < ND) {
            float s00 = S[q][dl],     s01 = S[q][dl + 1],     s02 = S[q][dl + 2];
            float s10 = S[q + 1][dl], s11 = S[q + 1][dl + 1], s12 = S[q + 1][dl + 2];
            float s20 = S[q + 2][dl], s21 = S[q + 2][dl + 1], s22 = S[q + 2][dl + 2];
            float m1 = -FLT_MAX, m2 = -FLT_MAX, m3 = -FLT_MAX;
            for (int f = 0; f < 32; ++f) {   // uniform scalar weight loads
                float v1 = c1w[f] * s00 + c1b[f];
                m1 = fmaxf(m1, v1);
                float v2 = c2b[f] + c2w[f*4+0]*s00 + c2w[f*4+1]*s01
                                  + c2w[f*4+2]*s10 + c2w[f*4+3]*s11;
                m2 = fmaxf(m2, v2);
                float v3 = c3b[f] + c3w[f*9+0]*s00 + c3w[f*9+1]*s01 + c3w[f*9+2]*s02
                                  + c3w[f*9+3]*s10 + c3w[f*9+4]*s11 + c3w[f*9+5]*s12
                                  + c3w[f*9+6]*s20 + c3w[f*9+7]*s21 + c3w[f*9+8]*s22;
                m3 = fmaxf(m3, v3);
            }
            m1 = fmaxf(m1, 0.f); m2 = fmaxf(m2, 0.f); m3 = fmaxf(m3, 0.f);
            ins2(a1[0], a2[0], m1); ins2(a1[1], a2[1], m2); ins2(a1[2], a2[2], m3);
        }
    }
    // merge the 4 lanes of each q within the wave (lanes q, q+16, q+32, q+48)
#pragma unroll
    for (int m = 16; m <= 32; m <<= 1) {
#pragma unroll
        for (int ng = 0; ng < 3; ++ng) {
            float b1v = __shfl_xor(a1[ng], m), b2v = __shfl_xor(a2[ng], m);
            merge2(a1[ng], a2[ng], b1v, b2v);
        }
    }
    __shared__ float PART[4][16][6];
    int wv = tid >> 6;
    if ((tid & 63) < 16) {
#pragma unroll
        for (int ng = 0; ng < 3; ++ng) {
            PART[wv][q][ng * 2]     = a1[ng];
            PART[wv][q][ng * 2 + 1] = a2[ng];
        }
    }
    __syncthreads();
    if (tid < 16) {
        float* c2p = ws + WS_C2 + ((size_t)(b * NQ + tid) * 3) * 8 + strip * 2;
#pragma unroll
        for (int ng = 0; ng < 3; ++ng) {
            float x1 = PART[0][tid][ng * 2], x2 = PART[0][tid][ng * 2 + 1];
            merge2(x1, x2, PART[1][tid][ng * 2], PART[1][tid][ng * 2 + 1]);
            merge2(x1, x2, PART[2][tid][ng * 2], PART[2][tid][ng * 2 + 1]);
            merge2(x1, x2, PART[3][tid][ng * 2], PART[3][tid][ng * 2 + 1]);
            c2p[ng * 8] = x1; c2p[ng * 8 + 1] = x2;
        }
    }
}

// ------- kmlp: merge conv strips + 208 -> 32 -> 32 -> 1 -------
__global__ __launch_bounds__(64) void kmlp(const float* __restrict__ w1,
                                           const float* __restrict__ b1,
                                           const float* __restrict__ w2,
                                           const float* __restrict__ b2,
                                           const float* __restrict__ w3,
                                           const float* __restrict__ b3,
                                           const float* __restrict__ ws,
                                           float* __restrict__ out) {
    int b = blockIdx.x, l = threadIdx.x;
    __shared__ float sc[208];
    __shared__ float h[32];
    const float* s = ws + WS_SCORES + (size_t)b * 208;
    for (int i = l; i < 208; i += 64)
        if ((i % 13) >= 6) sc[i] = s[i];       // slots 6..12 from WS_SCORES
    if (l < 48) {                               // slots 0..5 from strip merge
        int q = l / 3, ng = l % 3;
        const float* p = ws + WS_C2 + ((size_t)(b * NQ + q) * 3 + ng) * 8;
        float x1 = p[0], x2 = p[1];
        merge2(x1, x2, p[2], p[3]);
        merge2(x1, x2, p[4], p[5]);
        merge2(x1, x2, p[6], p[7]);
        sc[q * 13 + ng * 2] = x1; sc[q * 13 + ng * 2 + 1] = x2;
    }
    __syncthreads();
    int j = l & 31, half = l >> 5;
    float a = 0.f;
    int i0 = half * 104;
    for (int i = 0; i < 104; ++i) a += sc[i0 + i] * w1[(i0 + i) * 32 + j];
    a += __shfl_xor(a, 32);
    a = fmaxf(a + b1[j], 0.f);
    if (half == 0) h[j] = a;
    __syncthreads();
    float r = 0.f;
    if (half == 0) {
        float a2 = 0.f;
        for (int k = 0; k < 32; ++k) a2 += h[k] * w2[k * 32 + j];
        a2 = fmaxf(a2 + b2[j], 0.f);
        r = a2 * w3[j];
    }
#pragma unroll
    for (int m = 1; m <= 32; m <<= 1) r += __shfl_xor(r, m);
    if (l == 0) out[b] = r + b3[0];
}

extern "C" void kernel_launch(void* const* d_in, const int* in_sizes, int n_in,
                              void* d_out, int out_size, void* d_ws, size_t ws_size,
                              hipStream_t stream) {
    (void)in_sizes; (void)n_in; (void)out_size; (void)ws_size;
    const int*   qrls = (const int*)d_in[0];
    const int*   docw = (const int*)d_in[1];
    const float* emb  = (const float*)d_in[2];
    const float* idf  = (const float*)d_in[3];
    const float* c1w  = (const float*)d_in[4];
    const float* c1b  = (const float*)d_in[5];
    const float* c2w  = (const float*)d_in[6];
    const float* c2b  = (const float*)d_in[7];
    const float* c3w  = (const float*)d_in[8];
    const float* c3b  = (const float*)d_in[9];
    const float* w1   = (const float*)d_in[10];
    const float* b1   = (const float*)d_in[11];
    const float* w2   = (const float*)d_in[12];
    const float* b2   = (const float*)d_in[13];
    const float* w3   = (const float*)d_in[14];
    const float* b3   = (const float*)d_in[15];
    float* ws  = (float*)d_ws;
    float* out = (float*)d_out;

    kq<<<dim3(NB), 256, 0, stream>>>(qrls, emb, idf, ws);
    ksim<<<dim3(4, NB), 256, 0, stream>>>(docw, emb, ws);
    kctxtop<<<dim3(4, NB), 256, 0, stream>>>(ws);
    kconv<<<dim3(4, NB), 256, 0, stream>>>(c1w, c1b, c2w, c2b, c3w, c3b, ws);
    kmlp<<<dim3(NB), 64, 0, stream>>>(w1, b1, w2, b2, w3, b3, ws, out);
}

// Round 5
// 171.038 us; speedup vs baseline: 3.0095x; 1.0370x over previous
//
#include <hip/hip_runtime.h>
#include <float.h>
#include <math.h>

#define NB 128
#define NQ 16
#define ND 800
#define NE 300

// workspace layout (float offsets). All regions written every call.
#define WS_SIM    0                          // [NB][NQ][ND] raw dots (= cosine, unit rows)
#define WS_CTXINV (NB*NQ*ND)                 // [NB][ND] 1/(||ctx||/9+1e-9)
#define WS_SCORES (WS_CTXINV + NB*ND)        // [NB][NQ][13] (slots 6..12 used)
#define WS_C2     (WS_SCORES + NB*NQ*13)     // [NB][NQ][3][4 strips][2] partial top2
#define WS_QBF    (WS_C2 + NB*NQ*24)         // [NB][16][320] bf16 (q, zero-padded K)

typedef __attribute__((ext_vector_type(8))) short short8;
typedef __attribute__((ext_vector_type(4))) float f32x4;

__device__ __forceinline__ unsigned short f2bf(float x) {   // RNE fp32->bf16
    unsigned u = __float_as_uint(x);
    u += 0x7FFF + ((u >> 16) & 1);
    return (unsigned short)(u >> 16);
}

__device__ __forceinline__ void ins6(float t[6], float v) {
    if (v > t[5]) t[5] = v;
    float a;
    if (t[5] > t[4]) { a = t[4]; t[4] = t[5]; t[5] = a; }
    if (t[4] > t[3]) { a = t[3]; t[3] = t[4]; t[4] = a; }
    if (t[3] > t[2]) { a = t[2]; t[2] = t[3]; t[3] = a; }
    if (t[2] > t[1]) { a = t[1]; t[1] = t[2]; t[2] = a; }
    if (t[1] > t[0]) { a = t[0]; t[0] = t[1]; t[1] = a; }
}

__device__ __forceinline__ void ins2(float& a1, float& a2, float v) {
    if (v > a2) a2 = v;
    if (a2 > a1) { float t = a1; a1 = a2; a2 = t; }
}

__device__ __forceinline__ void merge2(float& a1, float& a2, float b1v, float b2v) {
    float hi = fmaxf(a1, b1v), lo = fminf(a1, b1v);
    a1 = hi;
    a2 = fmaxf(lo, fmaxf(a2, b2v));
}

// sliding sum of 8 consecutive lanes (this lane .. lane+7)
__device__ __forceinline__ float slide8(float s) {
    s += __shfl_down(s, 1);
    s += __shfl_down(s, 2);
    s += __shfl_down(s, 4);
    return s;
}

// ------- kq: q -> bf16 [16][320] (zero-padded) + idf -------
__global__ __launch_bounds__(256) void kq(const int* __restrict__ qrls,
                                          const float* __restrict__ emb,
                                          const float* __restrict__ idf,
                                          float* __restrict__ ws) {
    int b = blockIdx.x;
    int tid = threadIdx.x;
    unsigned short* qbf = (unsigned short*)(ws + WS_QBF) + (size_t)b * 16 * 320;
    for (int idx = tid; idx < 16 * 160; idx += 256) {
        int q = idx / 160, pr = idx % 160;
        int row = qrls[b * NQ + q];
        int e = pr * 2;
        float x0 = (e < NE) ? emb[(size_t)row * NE + e] : 0.f;
        float x1 = (e + 1 < NE) ? emb[(size_t)row * NE + e + 1] : 0.f;
        unsigned pack = (unsigned)f2bf(x0) | ((unsigned)f2bf(x1) << 16);
        *(unsigned*)(qbf + q * 320 + e) = pack;
    }
    if (tid < NQ) {
        int row = qrls[b * NQ + tid];
        ws[WS_SCORES + (b * NQ + tid) * 13 + 12] = idf[row];
    }
}

// ------- kfused: grid (65, NB), 64 thr (1 wave) -------
// bx < 50 : MFMA sim tile — 16 q x 16 d, K=320 (10 x mfma_f32_16x16x32_bf16).
//           A = q bf16 (preloaded frags), B = doc rows streamed fp32->bf16.
//           A zero-pad over K>=300 makes B tail garbage harmless.
// bx >= 50: ctx-norm chunk — 64 doc rows (4-row halo), slide8 window sums.
__global__ __launch_bounds__(64) void kfused(const int* __restrict__ docw,
                                             const float* __restrict__ emb,
                                             float* __restrict__ ws) {
    int b = blockIdx.y;
    int bx = blockIdx.x;
    int lane = threadIdx.x;

    if (bx < 50) {
        int tile = bx;
        int rsub = lane & 15;      // A-row (q) / B-col (d) selector
        int kgrp = lane >> 4;      // K sub-chunk: elems kgrp*8 .. +8
        const unsigned short* qb = (const unsigned short*)(ws + WS_QBF)
                                   + ((size_t)b * 16 + rsub) * 320 + kgrp * 8;
        short8 afr[10];
#pragma unroll
        for (int k = 0; k < 10; ++k)
            afr[k] = *(const short8*)(qb + k * 32);

        int drow = docw[b * ND + tile * 16 + rsub];
        const float* dp = emb + (size_t)drow * NE + kgrp * 8;

        f32x4 acc = {0.f, 0.f, 0.f, 0.f};
        float4 b0 = *(const float4*)(dp);
        float4 b1 = *(const float4*)(dp + 4);
#pragma unroll
        for (int k = 0; k < 10; ++k) {
            float4 n0, n1;
            if (k < 9) {                       // prefetch next K-step
                n0 = *(const float4*)(dp + (k + 1) * 32);
                n1 = *(const float4*)(dp + (k + 1) * 32 + 4);
            }
            short8 bf;
            bf[0] = (short)f2bf(b0.x); bf[1] = (short)f2bf(b0.y);
            bf[2] = (short)f2bf(b0.z); bf[3] = (short)f2bf(b0.w);
            bf[4] = (short)f2bf(b1.x); bf[5] = (short)f2bf(b1.y);
            bf[6] = (short)f2bf(b1.z); bf[7] = (short)f2bf(b1.w);
            acc = __builtin_amdgcn_mfma_f32_16x16x32_bf16(afr[k], bf, acc, 0, 0, 0);
            if (k < 9) { b0 = n0; b1 = n1; }
        }
        // C layout: col = lane&15, row = (lane>>4)*4 + i
        int col = tile * 16 + rsub;
        float* simp = ws + WS_SIM + (size_t)b * NQ * ND + col;
#pragma unroll
        for (int i = 0; i < 4; ++i)
            simp[(size_t)(kgrp * 4 + i) * ND] = acc[i];
    } else {
        int chunk = bx - 50;                    // 0..14
        int r = chunk * 56 - 4 + lane;
        bool ok = (r >= 0 && r < ND);
        const float4* dv = (const float4*)emb;
        if (ok) dv = (const float4*)(emb + (size_t)docw[b * ND + r] * NE);
        float sq = 0.f;
        float4 z4 = {0.f, 0.f, 0.f, 0.f};
        float4 v = ok ? dv[0] : z4;
        for (int e4 = 0; e4 < 75; ++e4) {
            float4 vn = (ok && e4 < 74) ? dv[e4 + 1] : z4;
            float s0 = slide8(v.x), s1 = slide8(v.y);
            float s2 = slide8(v.z), s3 = slide8(v.w);
            sq = fmaf(s0, s0, sq); sq = fmaf(s1, s1, sq);
            sq = fmaf(s2, s2, sq); sq = fmaf(s3, s3, sq);
            v = vn;
        }
        int d = chunk * 56 + lane;
        if (lane < 56 && d < ND)
            ws[WS_CTXINV + b * ND + d] = 1.f / (sqrtf(sq) * (1.f / 9.f) + 1e-9f);
    }
}

// ------- kctxtop: prefix scan of raw dots -> context cosine -> top-6 -------
__global__ __launch_bounds__(256) void kctxtop(float* __restrict__ ws) {
    int b = blockIdx.y;
    int w = threadIdx.x >> 6, lane = threadIdx.x & 63;
    int q = blockIdx.x * 4 + w;
    __shared__ float P[4][ND];
    const float* simrow = ws + WS_SIM + (size_t)(b * NQ + q) * ND;
    const float* cinv = ws + WS_CTXINV + b * ND;
    float carry = 0.f;
    for (int c = 0; c < 13; ++c) {
        int d = c * 64 + lane;
        float v = (d < ND) ? simrow[d] : 0.f;
#pragma unroll
        for (int off = 1; off < 64; off <<= 1) {
            float t = __shfl_up(v, off);
            if (lane >= off) v += t;
        }
        v += carry;
        if (d < ND) P[w][d] = v;
        carry = __shfl(v, 63);
    }
    __syncthreads();
    float top[6] = {-FLT_MAX,-FLT_MAX,-FLT_MAX,-FLT_MAX,-FLT_MAX,-FLT_MAX};
    for (int c = 0; c < 13; ++c) {
        int d = c * 64 + lane;
        if (d < ND) {
            int hi_i = (d + 3 < ND) ? d + 3 : ND - 1;
            float hi = P[w][hi_i];
            float lo = (d >= 5) ? P[w][d - 5] : 0.f;
            float ctx = (hi - lo) * (1.f / 9.f) * cinv[d];
            ins6(top, ctx);
        }
    }
#pragma unroll
    for (int m = 1; m < 64; m <<= 1) {
        float o0 = __shfl_xor(top[0], m), o1 = __shfl_xor(top[1], m);
        float o2 = __shfl_xor(top[2], m), o3 = __shfl_xor(top[3], m);
        float o4 = __shfl_xor(top[4], m), o5 = __shfl_xor(top[5], m);
        ins6(top, o0); ins6(top, o1); ins6(top, o2);
        ins6(top, o3); ins6(top, o4); ins6(top, o5);
    }
    if (lane == 0) {
        float* sc = ws + WS_SCORES + (size_t)(b * NQ + q) * 13;
        sc[6] = top[0]; sc[7] = top[1]; sc[8]  = top[2];
        sc[9] = top[3]; sc[10] = top[4]; sc[11] = top[5];
    }
}

// ------- kconv: all 16 q, 200-d strip per block; partial top2 -> WS_C2 -------
__global__ __launch_bounds__(256) void kconv(const float* __restrict__ c1w,
                                             const float* __restrict__ c1b,
                                             const float* __restrict__ c2w,
                                             const float* __restrict__ c2b,
                                             const float* __restrict__ c3w,
                                             const float* __restrict__ c3b,
                                             float* __restrict__ ws) {
    int b = blockIdx.y;
    int strip = blockIdx.x;
    int c0 = strip * 200;
    int tid = threadIdx.x;
    __shared__ float S[18][204];   // rows 16,17 zero-padded; 2-col halo
    for (int idx = tid; idx < 18 * 202; idx += 256) {
        int row = idx / 202, col = idx % 202;
        int c = c0 + col;
        float v = 0.f;
        if (row < NQ && c < ND) v = ws[WS_SIM + (size_t)(b * NQ + row) * ND + c];
        S[row][col] = v;
    }
    __syncthreads();
    int q = tid & 15, dg = tid >> 4;   // 16 q x 16 d-groups
    float a1[3] = {-FLT_MAX,-FLT_MAX,-FLT_MAX};
    float a2[3] = {-FLT_MAX,-FLT_MAX,-FLT_MAX};
    for (int j = 0; j < 13; ++j) {
        int dl = dg + j * 16;
        if (dl < 200 && c0 + dl < ND) {
            float s00 = S[q][dl],     s01 = S[q][dl + 1],     s02 = S[q][dl + 2];
            float s10 = S[q + 1][dl], s11 = S[q + 1][dl + 1], s12 = S[q + 1][dl + 2];
            float s20 = S[q + 2][dl], s21 = S[q + 2][dl + 1], s22 = S[q + 2][dl + 2];
            float m1 = -FLT_MAX, m2 = -FLT_MAX, m3 = -FLT_MAX;
            for (int f = 0; f < 32; ++f) {   // uniform scalar weight loads
                float v1 = c1w[f] * s00 + c1b[f];
                m1 = fmaxf(m1, v1);
                float v2 = c2b[f] + c2w[f*4+0]*s00 + c2w[f*4+1]*s01
                                  + c2w[f*4+2]*s10 + c2w[f*4+3]*s11;
                m2 = fmaxf(m2, v2);
                float v3 = c3b[f] + c3w[f*9+0]*s00 + c3w[f*9+1]*s01 + c3w[f*9+2]*s02
                                  + c3w[f*9+3]*s10 + c3w[f*9+4]*s11 + c3w[f*9+5]*s12
                                  + c3w[f*9+6]*s20 + c3w[f*9+7]*s21 + c3w[f*9+8]*s22;
                m3 = fmaxf(m3, v3);
            }
            m1 = fmaxf(m1, 0.f); m2 = fmaxf(m2, 0.f); m3 = fmaxf(m3, 0.f);
            ins2(a1[0], a2[0], m1); ins2(a1[1], a2[1], m2); ins2(a1[2], a2[2], m3);
        }
    }
    // merge the 4 lanes of each q within the wave (lanes q, q+16, q+32, q+48)
#pragma unroll
    for (int m = 16; m <= 32; m <<= 1) {
#pragma unroll
        for (int ng = 0; ng < 3; ++ng) {
            float b1v = __shfl_xor(a1[ng], m), b2v = __shfl_xor(a2[ng], m);
            merge2(a1[ng], a2[ng], b1v, b2v);
        }
    }
    __shared__ float PART[4][16][6];
    int wv = tid >> 6;
    if ((tid & 63) < 16) {
#pragma unroll
        for (int ng = 0; ng < 3; ++ng) {
            PART[wv][q][ng * 2]     = a1[ng];
            PART[wv][q][ng * 2 + 1] = a2[ng];
        }
    }
    __syncthreads();
    if (tid < 16) {
        float* c2p = ws + WS_C2 + ((size_t)(b * NQ + tid) * 3) * 8 + strip * 2;
#pragma unroll
        for (int ng = 0; ng < 3; ++ng) {
            float x1 = PART[0][tid][ng * 2], x2 = PART[0][tid][ng * 2 + 1];
            merge2(x1, x2, PART[1][tid][ng * 2], PART[1][tid][ng * 2 + 1]);
            merge2(x1, x2, PART[2][tid][ng * 2], PART[2][tid][ng * 2 + 1]);
            merge2(x1, x2, PART[3][tid][ng * 2], PART[3][tid][ng * 2 + 1]);
            c2p[ng * 8] = x1; c2p[ng * 8 + 1] = x2;
        }
    }
}

// ------- kmlp: merge conv strips + 208 -> 32 -> 32 -> 1 -------
__global__ __launch_bounds__(64) void kmlp(const float* __restrict__ w1,
                                           const float* __restrict__ b1,
                                           const float* __restrict__ w2,
                                           const float* __restrict__ b2,
                                           const float* __restrict__ w3,
                                           const float* __restrict__ b3,
                                           const float* __restrict__ ws,
                                           float* __restrict__ out) {
    int b = blockIdx.x, l = threadIdx.x;
    __shared__ float sc[208];
    __shared__ float h[32];
    const float* s = ws + WS_SCORES + (size_t)b * 208;
    for (int i = l; i < 208; i += 64)
        if ((i % 13) >= 6) sc[i] = s[i];       // slots 6..12 from WS_SCORES
    if (l < 48) {                               // slots 0..5 from strip merge
        int q = l / 3, ng = l % 3;
        const float* p = ws + WS_C2 + ((size_t)(b * NQ + q) * 3 + ng) * 8;
        float x1 = p[0], x2 = p[1];
        merge2(x1, x2, p[2], p[3]);
        merge2(x1, x2, p[4], p[5]);
        merge2(x1, x2, p[6], p[7]);
        sc[q * 13 + ng * 2] = x1; sc[q * 13 + ng * 2 + 1] = x2;
    }
    __syncthreads();
    int j = l & 31, half = l >> 5;
    float a = 0.f;
    int i0 = half * 104;
    for (int i = 0; i < 104; ++i) a += sc[i0 + i] * w1[(i0 + i) * 32 + j];
    a += __shfl_xor(a, 32);
    a = fmaxf(a + b1[j], 0.f);
    if (half == 0) h[j] = a;
    __syncthreads();
    float r = 0.f;
    if (half == 0) {
        float a2 = 0.f;
        for (int k = 0; k < 32; ++k) a2 += h[k] * w2[k * 32 + j];
        a2 = fmaxf(a2 + b2[j], 0.f);
        r = a2 * w3[j];
    }
#pragma unroll
    for (int m = 1; m <= 32; m <<= 1) r += __shfl_xor(r, m);
    if (l == 0) out[b] = r + b3[0];
}

extern "C" void kernel_launch(void* const* d_in, const int* in_sizes, int n_in,
                              void* d_out, int out_size, void* d_ws, size_t ws_size,
                              hipStream_t stream) {
    (void)in_sizes; (void)n_in; (void)out_size; (void)ws_size;
    const int*   qrls = (const int*)d_in[0];
    const int*   docw = (const int*)d_in[1];
    const float* emb  = (const float*)d_in[2];
    const float* idf  = (const float*)d_in[3];
    const float* c1w  = (const float*)d_in[4];
    const float* c1b  = (const float*)d_in[5];
    const float* c2w  = (const float*)d_in[6];
    const float* c2b  = (const float*)d_in[7];
    const float* c3w  = (const float*)d_in[8];
    const float* c3b  = (const float*)d_in[9];
    const float* w1   = (const float*)d_in[10];
    const float* b1   = (const float*)d_in[11];
    const float* w2   = (const float*)d_in[12];
    const float* b2   = (const float*)d_in[13];
    const float* w3   = (const float*)d_in[14];
    const float* b3   = (const float*)d_in[15];
    float* ws  = (float*)d_ws;
    float* out = (float*)d_out;

    kq<<<dim3(NB), 256, 0, stream>>>(qrls, emb, idf, ws);
    kfused<<<dim3(65, NB), 64, 0, stream>>>(docw, emb, ws);
    kctxtop<<<dim3(4, NB), 256, 0, stream>>>(ws);
    kconv<<<dim3(4, NB), 256, 0, stream>>>(c1w, c1b, c2w, c2b, c3w, c3b, ws);
    kmlp<<<dim3(NB), 64, 0, stream>>>(w1, b1, w2, b2, w3, b3, ws, out);
}